// Round 3
// baseline (1826.141 us; speedup 1.0000x reference)
//
#include <hip/hip_runtime.h>
#include <cstddef>

#define NB 4096
#define NT 64
#define NOBS 64
#define NH 64
#define NA 8
#define NS 201

// d_out layout (floats):
//   logits [B,T,A]  @ 0          (2097152)
//   values [T*B]    @ 2097152    (262144)
//   stack  [B,S,H]  @ 2359296    (52690944)
//   ptrs   [B]      @ 55050240   (4096, stored as float)

__global__ void copy_stack_kernel(const float4* __restrict__ src,
                                  float4* __restrict__ dst, int n4) {
    int i = blockIdx.x * blockDim.x + threadIdx.x;
    int stride = gridDim.x * blockDim.x;
    for (; i < n4; i += stride) dst[i] = src[i];
}

__launch_bounds__(256, 2)
__global__ void stacknet_kernel(const float* __restrict__ x,
                                const int* __restrict__ ptrs_in,
                                const float* __restrict__ W1,
                                const float* __restrict__ b1,
                                const float* __restrict__ W2,
                                const float* __restrict__ b2,
                                const float* __restrict__ Ws,
                                const float* __restrict__ bs,
                                const float* __restrict__ Wp,
                                const float* __restrict__ bp,
                                const float* __restrict__ Wv,
                                const float* __restrict__ bv,
                                float* __restrict__ logits_out,
                                float* __restrict__ values_out,
                                float* __restrict__ stack,
                                float* __restrict__ ptrs_out) {
    const int lane = threadIdx.x & 63;
    const int wv = threadIdx.x >> 6;
    const int bA = (blockIdx.x << 2) + wv;       // 0..2047
    const int bB = bA + 2048;                    // 2048..4095
    const int aa = lane & 15;                    // head index (0..11 valid)

    // Head weights laid out [a][k] with row pad 68 floats (16B-aligned rows,
    // conflict-free b128 reads: start bank 4*(aa+j) distinct within 8-lane phase).
    __shared__ __align__(16) float shw[16 * 68];
    __shared__ float shb[16];
    // Per wave, per slot: [0..63]=x_t, [64..127]=top, [128..191]=h, [192..255]=p
    __shared__ __align__(16) float vbuf[4][2][256];

    for (int i = threadIdx.x; i < 16 * 64; i += 256) {
        int a = i >> 6, k = i & 63;
        float w = 0.0f;
        if (a < 3)        w = Ws[a * 64 + k];
        else if (a < 11)  w = Wp[(a - 3) * 64 + k];
        else if (a == 11) w = Wv[k];
        shw[a * 68 + k] = w;
    }
    if (threadIdx.x < 16) {
        int a = threadIdx.x;
        float bb = 0.0f;
        if (a < 3) bb = bs[a];
        else if (a < 11) bb = bp[a - 3];
        else if (a == 11) bb = bv[0];
        shb[a] = bb;
    }
    __syncthreads();

    // W1 row `lane` (128 floats) and W2 row `lane` (64 floats) in registers
    // (unified VGPR/AGPR file). Shared by both batch slots.
    float w1r[128];
#pragma unroll
    for (int j = 0; j < 32; ++j) {
        float4 tW = ((const float4*)W1)[lane * 32 + j];
        w1r[4*j] = tW.x; w1r[4*j+1] = tW.y; w1r[4*j+2] = tW.z; w1r[4*j+3] = tW.w;
    }
    float w2r[64];
#pragma unroll
    for (int j = 0; j < 16; ++j) {
        float4 tW = ((const float4*)W2)[lane * 16 + j];
        w2r[4*j] = tW.x; w2r[4*j+1] = tW.y; w2r[4*j+2] = tW.z; w2r[4*j+3] = tW.w;
    }
    float b1r = b1[lane];
    float b2r = b2[lane];

    int ptrA = ptrs_in[bA];
    int ptrB = ptrs_in[bB];
    const float* xbA = x + (size_t)bA * NT * NOBS;
    const float* xbB = x + (size_t)bB * NT * NOBS;
    float* stkA = stack + (size_t)bA * NS * NH;
    float* stkB = stack + (size_t)bB * NS * NH;
    float* lgbA = logits_out + (size_t)bA * NT * NA;
    float* lgbB = logits_out + (size_t)bB * NT * NA;

    float* vA = &vbuf[wv][0][0];
    float* vB = &vbuf[wv][1][0];
    const float* shwa = &shw[aa * 68];
    const float shba = shb[aa];

    // Initial top + x
    float topA = stkA[ptrA * 64 + lane];
    float topB = stkB[ptrB * 64 + lane];
    float xA = xbA[lane];
    float xB = xbB[lane];

    bool pushedA = false, pushedB = false;
    float pushvalA = 0.0f, pushvalB = 0.0f;

    for (int t = 0; t < NT; ++t) {
        // ---- Prefetch: candidates for next step's top + next x ----
        int r0A = (ptrA > 0) ? (ptrA - 1) : 0;
        int r0B = (ptrB > 0) ? (ptrB - 1) : 0;
        float c0A = stkA[r0A * 64 + lane];
        float c1A = stkA[ptrA * 64 + lane];
        float c2A = stkA[(ptrA + 1) * 64 + lane];
        float c0B = stkB[r0B * 64 + lane];
        float c1B = stkB[ptrB * 64 + lane];
        float c2B = stkB[(ptrB + 1) * 64 + lane];
        int tn = (t + 1 < NT) ? (t + 1) : t;
        float xnA = xbA[tn * 64 + lane];
        float xnB = xbB[tn * 64 + lane];

        // ---- Stage x_t and top into LDS for broadcast ----
        vA[lane]      = xA;
        vA[64 + lane] = topA;
        vB[lane]      = xB;
        vB[64 + lane] = topB;

        // ---- h = tanh( dot(W1_row, [x|top]) + b1 ), sequential k ----
        float accA = 0.0f, accB = 0.0f;
        const float4* vA4 = (const float4*)vA;
        const float4* vB4 = (const float4*)vB;
#pragma unroll
        for (int j = 0; j < 32; ++j) {
            float4 a4 = vA4[j];
            float4 b4 = vB4[j];
            accA = fmaf(w1r[4*j],   a4.x, accA);
            accA = fmaf(w1r[4*j+1], a4.y, accA);
            accA = fmaf(w1r[4*j+2], a4.z, accA);
            accA = fmaf(w1r[4*j+3], a4.w, accA);
            accB = fmaf(w1r[4*j],   b4.x, accB);
            accB = fmaf(w1r[4*j+1], b4.y, accB);
            accB = fmaf(w1r[4*j+2], b4.z, accB);
            accB = fmaf(w1r[4*j+3], b4.w, accB);
        }
        float hA = tanhf(accA + b1r);
        float hB = tanhf(accB + b1r);
        vA[128 + lane] = hA;
        vB[128 + lane] = hB;

        // ---- p = tanh( dot(W2_row, h) + b2 ) ----
        float a2A = 0.0f, a2B = 0.0f;
        const float4* hA4 = (const float4*)(vA + 128);
        const float4* hB4 = (const float4*)(vB + 128);
#pragma unroll
        for (int j = 0; j < 16; ++j) {
            float4 a4 = hA4[j];
            float4 b4 = hB4[j];
            a2A = fmaf(w2r[4*j],   a4.x, a2A);
            a2A = fmaf(w2r[4*j+1], a4.y, a2A);
            a2A = fmaf(w2r[4*j+2], a4.z, a2A);
            a2A = fmaf(w2r[4*j+3], a4.w, a2A);
            a2B = fmaf(w2r[4*j],   b4.x, a2B);
            a2B = fmaf(w2r[4*j+1], b4.y, a2B);
            a2B = fmaf(w2r[4*j+2], b4.z, a2B);
            a2B = fmaf(w2r[4*j+3], b4.w, a2B);
        }
        float pA = tanhf(a2A + b2r);
        float pB = tanhf(a2B + b2r);
        vA[192 + lane] = pA;
        vB[192 + lane] = pB;

        // ---- 12 head dots, lane aa = head aa, sequential k via b128 ----
        float haccA = 0.0f, haccB = 0.0f;
        const float4* pA4 = (const float4*)(vA + 192);
        const float4* pB4 = (const float4*)(vB + 192);
#pragma unroll
        for (int j = 0; j < 16; ++j) {
            float4 w4 = *(const float4*)(shwa + 4*j);
            float4 a4 = pA4[j];
            float4 b4 = pB4[j];
            haccA = fmaf(a4.x, w4.x, haccA);
            haccA = fmaf(a4.y, w4.y, haccA);
            haccA = fmaf(a4.z, w4.z, haccA);
            haccA = fmaf(a4.w, w4.w, haccA);
            haccB = fmaf(b4.x, w4.x, haccB);
            haccB = fmaf(b4.y, w4.y, haccB);
            haccB = fmaf(b4.z, w4.z, haccB);
            haccB = fmaf(b4.w, w4.w, haccB);
        }
        float svA = haccA + shba;
        float svB = haccB + shba;

        // ---- decision (wave-uniform), softmax mimic, first strict max ----
        float s0A = __shfl(svA, 0, 64), s1A = __shfl(svA, 1, 64), s2A = __shfl(svA, 2, 64);
        float s0B = __shfl(svB, 0, 64), s1B = __shfl(svB, 1, 64), s2B = __shfl(svB, 2, 64);

        float mA = fmaxf(fmaxf(s0A, s1A), s2A);
        float e0A = expf(s0A - mA), e1A = expf(s1A - mA), e2A = expf(s2A - mA);
        float SA = (e0A + e1A) + e2A;
        float p0A = e0A / SA, p1A = e1A / SA, p2A = e2A / SA;
        int opA = 0; float pmA = p0A;
        if (p1A > pmA) { pmA = p1A; opA = 1; }
        if (p2A > pmA) { opA = 2; }

        float mB = fmaxf(fmaxf(s0B, s1B), s2B);
        float e0B = expf(s0B - mB), e1B = expf(s1B - mB), e2B = expf(s2B - mB);
        float SB = (e0B + e1B) + e2B;
        float p0B = e0B / SB, p1B = e1B / SB, p2B = e2B / SB;
        int opB = 0; float pmB = p0B;
        if (p1B > pmB) { pmB = p1B; opB = 1; }
        if (p2B > pmB) { opB = 2; }

        // ---- push writes ----
        if (opA == 2) stkA[ptrA * 64 + lane] = pA;
        if (opB == 2) stkB[ptrB * 64 + lane] = pB;

        // ---- select next top from prefetched candidates; forward the
        //      one-iteration store->load race via the pushval register ----
        float selA = (opA == 0) ? c0A : ((opA == 1) ? c1A : c2A);
        if (opA == 0 && pushedA) selA = pushvalA;   // c0 row == prev pushed row
        float selB = (opB == 0) ? c0B : ((opB == 1) ? c1B : c2B);
        if (opB == 0 && pushedB) selB = pushvalB;

        pushedA = (opA == 2); pushvalA = pA;
        pushedB = (opB == 2); pushvalB = pB;

        int nA = ptrA + opA - 1; ptrA = (nA < 0) ? 0 : nA;
        int nB = ptrB + opB - 1; ptrB = (nB < 0) ? 0 : nB;
        topA = selA; topB = selB;
        xA = xnA; xB = xnB;

        // ---- outputs: lanes 3..10 -> logits, lane 11 -> value ----
        if (lane >= 3 && lane <= 10) {
            lgbA[t * NA + (lane - 3)] = svA;
            lgbB[t * NA + (lane - 3)] = svB;
        }
        if (lane == 11) {
            values_out[(size_t)t * NB + bA] = svA;
            values_out[(size_t)t * NB + bB] = svB;
        }
    }
    if (lane == 0) {
        ptrs_out[bA] = (float)ptrA;
        ptrs_out[bB] = (float)ptrB;
    }
}

extern "C" void kernel_launch(void* const* d_in, const int* in_sizes, int n_in,
                              void* d_out, int out_size, void* d_ws, size_t ws_size,
                              hipStream_t stream) {
    const float* x        = (const float*)d_in[0];
    const float* stack_in = (const float*)d_in[1];
    const int*   ptrs_in  = (const int*)d_in[2];
    const float* W1 = (const float*)d_in[3];
    const float* b1 = (const float*)d_in[4];
    const float* W2 = (const float*)d_in[5];
    const float* b2 = (const float*)d_in[6];
    const float* Ws = (const float*)d_in[7];
    const float* bs = (const float*)d_in[8];
    const float* Wp = (const float*)d_in[9];
    const float* bp = (const float*)d_in[10];
    const float* Wv = (const float*)d_in[11];
    const float* bv = (const float*)d_in[12];

    float* out      = (float*)d_out;
    float* logits   = out;                 // 2097152
    float* values   = out + 2097152;       // 262144
    float* stack    = out + 2359296;       // 52690944
    float* ptrs_out = out + 55050240;      // 4096

    int n4 = 52690944 / 4;
    copy_stack_kernel<<<4096, 256, 0, stream>>>((const float4*)stack_in,
                                                (float4*)stack, n4);
    stacknet_kernel<<<512, 256, 0, stream>>>(x, ptrs_in, W1, b1, W2, b2,
                                             Ws, bs, Wp, bp, Wv, bv,
                                             logits, values, stack, ptrs_out);
}

// Round 4
// 742.807 us; speedup vs baseline: 2.4584x; 2.4584x over previous
//
#include <hip/hip_runtime.h>
#include <cstddef>

#define NB 4096
#define NT 64
#define NOBS 64
#define NH 64
#define NA 8
#define NS 201

// d_out layout (floats):
//   logits [B,T,A]  @ 0          (2097152)
//   values [T*B]    @ 2097152    (262144)
//   stack  [B,S,H]  @ 2359296    (52690944)
//   ptrs   [B]      @ 55050240   (4096, stored as float)

__global__ void copy_stack_kernel(const float4* __restrict__ src,
                                  float4* __restrict__ dst, int n4) {
    int i = blockIdx.x * blockDim.x + threadIdx.x;
    if (i < n4) dst[i] = src[i];
}

__launch_bounds__(256, 2)
__global__ void stacknet_kernel(const float* __restrict__ x,
                                const int* __restrict__ ptrs_in,
                                const float* __restrict__ W1,
                                const float* __restrict__ b1,
                                const float* __restrict__ W2,
                                const float* __restrict__ b2,
                                const float* __restrict__ Ws,
                                const float* __restrict__ bs,
                                const float* __restrict__ Wp,
                                const float* __restrict__ bp,
                                const float* __restrict__ Wv,
                                const float* __restrict__ bv,
                                float* __restrict__ logits_out,
                                float* __restrict__ values_out,
                                float* __restrict__ stack,
                                float* __restrict__ ptrs_out) {
    const int lane = threadIdx.x & 63;
    const int wv = threadIdx.x >> 6;
    const int b = (blockIdx.x << 2) + wv;
    const int aa = lane & 15;                    // head index (0..11 valid)

    // Head weights [a][k], row pad 68 floats (16B-aligned rows for b128).
    __shared__ __align__(16) float shw[16 * 68];
    __shared__ float shb[16];
    // Per wave: [0..63]=x_t, [64..127]=top, [128..191]=h, [192..255]=p
    __shared__ __align__(16) float vbuf[4][256];

    for (int i = threadIdx.x; i < 16 * 64; i += 256) {
        int a = i >> 6, k = i & 63;
        float w = 0.0f;
        if (a < 3)        w = Ws[a * 64 + k];
        else if (a < 11)  w = Wp[(a - 3) * 64 + k];
        else if (a == 11) w = Wv[k];
        shw[a * 68 + k] = w;
    }
    if (threadIdx.x < 16) {
        int a = threadIdx.x;
        float bb = 0.0f;
        if (a < 3) bb = bs[a];
        else if (a < 11) bb = bp[a - 3];
        else if (a == 11) bb = bv[0];
        shb[a] = bb;
    }
    __syncthreads();

    // W1 row `lane` (128 floats) and W2 row `lane` (64 floats) in registers
    // (unified VGPR/AGPR file). NOTE: this kernel sits just under the
    // 256-reg/wave (2 waves/SIMD) cliff — R3's extra slot spilled to scratch
    // (FETCH 39MB -> 2.7GB). Keep long-lived register count minimal.
    float w1r[128];
#pragma unroll
    for (int j = 0; j < 32; ++j) {
        float4 tW = ((const float4*)W1)[lane * 32 + j];
        w1r[4*j] = tW.x; w1r[4*j+1] = tW.y; w1r[4*j+2] = tW.z; w1r[4*j+3] = tW.w;
    }
    float w2r[64];
#pragma unroll
    for (int j = 0; j < 16; ++j) {
        float4 tW = ((const float4*)W2)[lane * 16 + j];
        w2r[4*j] = tW.x; w2r[4*j+1] = tW.y; w2r[4*j+2] = tW.z; w2r[4*j+3] = tW.w;
    }
    float b1r = b1[lane];
    float b2r = b2[lane];

    int ptr = ptrs_in[b];
    const float* xb  = x + (size_t)b * NT * NOBS;
    float* stk       = stack + (size_t)b * NS * NH;
    float* lgb       = logits_out + (size_t)b * NT * NA;

    float* v = &vbuf[wv][0];
    const float* shwa = &shw[aa * 68];
    const float shba = shb[aa];

    float top = stk[ptr * 64 + lane];
    bool pushed = false;
    float pushval = 0.0f;

    for (int t = 0; t < NT; ++t) {
        // ---- Prefetch pop/push candidates for the next top.
        //      (noop candidate == current `top` register, no load needed) ----
        int r0 = (ptr > 0) ? (ptr - 1) : 0;
        float c0 = stk[r0 * 64 + lane];
        float c2 = stk[(ptr + 1) * 64 + lane];
        float xv = xb[t * 64 + lane];

        v[lane]      = xv;
        v[64 + lane] = top;

        // ---- h = tanh( dot(W1_row, [x|top]) + b1 ), sequential k (BLAS order) ----
        float acc = 0.0f;
        const float4* v4 = (const float4*)v;
#pragma unroll
        for (int j = 0; j < 32; ++j) {
            float4 a4 = v4[j];                  // same-addr broadcast read
            acc = fmaf(w1r[4*j],   a4.x, acc);
            acc = fmaf(w1r[4*j+1], a4.y, acc);
            acc = fmaf(w1r[4*j+2], a4.z, acc);
            acc = fmaf(w1r[4*j+3], a4.w, acc);
        }
        float h = tanhf(acc + b1r);
        v[128 + lane] = h;

        // ---- p = tanh( dot(W2_row, h) + b2 ) ----
        float acc2 = 0.0f;
        const float4* h4 = (const float4*)(v + 128);
#pragma unroll
        for (int j = 0; j < 16; ++j) {
            float4 a4 = h4[j];
            acc2 = fmaf(w2r[4*j],   a4.x, acc2);
            acc2 = fmaf(w2r[4*j+1], a4.y, acc2);
            acc2 = fmaf(w2r[4*j+2], a4.z, acc2);
            acc2 = fmaf(w2r[4*j+3], a4.w, acc2);
        }
        float p = tanhf(acc2 + b2r);
        v[192 + lane] = p;

        // ---- 12 head dots, lane aa = head aa, sequential k via b128 ----
        float hacc = 0.0f;
        const float4* p4 = (const float4*)(v + 192);
#pragma unroll
        for (int j = 0; j < 16; ++j) {
            float4 w4 = *(const float4*)(shwa + 4*j);
            float4 a4 = p4[j];
            hacc = fmaf(a4.x, w4.x, hacc);
            hacc = fmaf(a4.y, w4.y, hacc);
            hacc = fmaf(a4.z, w4.z, hacc);
            hacc = fmaf(a4.w, w4.w, hacc);
        }
        float sv = hacc + shba;

        // ---- decision (wave-uniform), softmax mimic, first strict max ----
        float s0 = __shfl(sv, 0, 64), s1 = __shfl(sv, 1, 64), s2 = __shfl(sv, 2, 64);
        float m = fmaxf(fmaxf(s0, s1), s2);
        float e0 = expf(s0 - m), e1 = expf(s1 - m), e2 = expf(s2 - m);
        float S = (e0 + e1) + e2;
        float p0 = e0 / S, p1 = e1 / S, p2 = e2 / S;
        int op = 0; float pm = p0;
        if (p1 > pm) { pm = p1; op = 1; }
        if (p2 > pm) { op = 2; }

        if (op == 2) stk[ptr * 64 + lane] = p;

        // Next top: pop -> c0 (or forwarded pushval if the pop target is the
        // row pushed LAST iteration — store may not have drained); noop -> top;
        // push -> c2 (row above, never written by us this iteration).
        float sel = (op == 0) ? (pushed ? pushval : c0)
                              : ((op == 1) ? top : c2);
        pushed = (op == 2);
        pushval = p;

        int np = ptr + op - 1;
        ptr = (np < 0) ? 0 : np;
        top = sel;

        // ---- outputs: lanes 3..10 -> logits, lane 11 -> value ----
        if (lane >= 3 && lane <= 10) {
            lgb[t * NA + (lane - 3)] = sv;
        }
        if (lane == 11) {
            values_out[(size_t)t * NB + b] = sv;
        }
    }
    if (lane == 0) ptrs_out[b] = (float)ptr;
}

extern "C" void kernel_launch(void* const* d_in, const int* in_sizes, int n_in,
                              void* d_out, int out_size, void* d_ws, size_t ws_size,
                              hipStream_t stream) {
    const float* x        = (const float*)d_in[0];
    const float* stack_in = (const float*)d_in[1];
    const int*   ptrs_in  = (const int*)d_in[2];
    const float* W1 = (const float*)d_in[3];
    const float* b1 = (const float*)d_in[4];
    const float* W2 = (const float*)d_in[5];
    const float* b2 = (const float*)d_in[6];
    const float* Ws = (const float*)d_in[7];
    const float* bs = (const float*)d_in[8];
    const float* Wp = (const float*)d_in[9];
    const float* bp = (const float*)d_in[10];
    const float* Wv = (const float*)d_in[11];
    const float* bv = (const float*)d_in[12];

    float* out      = (float*)d_out;
    float* logits   = out;                 // 2097152
    float* values   = out + 2097152;       // 262144
    float* stack    = out + 2359296;       // 52690944
    float* ptrs_out = out + 55050240;      // 4096

    int n4 = 52690944 / 4;                 // 13172736 = 51456 * 256
    copy_stack_kernel<<<51456, 256, 0, stream>>>((const float4*)stack_in,
                                                 (float4*)stack, n4);
    stacknet_kernel<<<1024, 256, 0, stream>>>(x, ptrs_in, W1, b1, W2, b2,
                                              Ws, bs, Wp, bp, Wv, bv,
                                              logits, values, stack, ptrs_out);
}